// Round 2
// 159.470 us; speedup vs baseline: 1.0587x; 1.0587x over previous
//
#include <hip/hip_runtime.h>

#define B_ 8
#define N_ 1024
#define E_ 128
#define T_ 16
#define M_ 256

#define UT_STRIDE 1088   // Ut/xt row pad (shorts): 2176B, breaks pow2 channel/bank aliasing
#define UB_STRIDE 272    // Ubf row pad (shorts): 544B
#define PP 136           // P-tile LDS pitch (shorts) = 272B = 17x16B: aligned b128, 2-way banks

typedef __attribute__((ext_vector_type(8))) short bf16x8;
typedef __attribute__((ext_vector_type(4))) float f32x4;

__device__ __forceinline__ unsigned short f32_to_bf16_rn(float f) {
  unsigned u = __float_as_uint(f);
  u = (u + 0x7fffu + ((u >> 16) & 1u)) >> 16;
  return (unsigned short)u;
}

// ---------------------------------------------------------------------------
// kprep: fused {U-transpose tiles | x-transpose tiles | RK4 propagator build}.
// grid(1024): bid<512 U-tiles (mt 4 x nt 16 x b 8); bid<768 x-tiles (256:
// et 2 x it 16 x b 8); else pbuild m = bid-768.
// Overlaps HBM-bound transposes with pbuild compute; 3 launches -> 1.
// ---------------------------------------------------------------------------
__global__ __launch_bounds__(256) void kprep(const float* __restrict__ U,
                                             const float* __restrict__ x,
                                             const float* __restrict__ W,
                                             unsigned short* __restrict__ Ubf,
                                             unsigned short* __restrict__ Ut,
                                             unsigned short* __restrict__ xt,
                                             unsigned short* __restrict__ PgT) {
  __shared__ __align__(16) unsigned short S[2 * 128 * PP];  // 69632 B (2 blocks/CU)
  const int bid = blockIdx.x, t = threadIdx.x;

  if (bid < 768) {
    // ---- 64x64 f32->bf16 transpose tile (U or x) ----
    unsigned short* L = S;  // [64][72]
    const int r = t >> 2, c16 = (t & 3) * 16;
    const float* src;
    unsigned short* dA = nullptr;
    unsigned short* dTbase;
    if (bid < 512) {
      const int m0 = (bid & 3) * 64, n0 = ((bid >> 2) & 15) * 64, b = bid >> 6;
      src = U + ((size_t)(b * N_ + n0 + r)) * N_ + m0 + c16;
      dA = Ubf + ((size_t)(b * N_ + n0 + r)) * UB_STRIDE + m0 + c16;
      dTbase = Ut + ((size_t)(b * M_ + m0)) * UT_STRIDE + n0;
    } else {
      const int u = bid - 512;  // 0..255: et 2 x it 16 x b 8
      const int e0 = (u & 1) * 64, i0 = ((u >> 1) & 15) * 64, b = u >> 5;
      src = x + ((size_t)(b * N_ + i0 + r)) * E_ + e0 + c16;
      dTbase = xt + ((size_t)(b * E_ + e0)) * UT_STRIDE + i0;
    }
    unsigned wbuf[8];
#pragma unroll
    for (int u = 0; u < 4; ++u) {
      const float4 v = ((const float4*)src)[u];
      wbuf[2 * u + 0] = (unsigned)f32_to_bf16_rn(v.x) | ((unsigned)f32_to_bf16_rn(v.y) << 16);
      wbuf[2 * u + 1] = (unsigned)f32_to_bf16_rn(v.z) | ((unsigned)f32_to_bf16_rn(v.w) << 16);
    }
    *(uint4*)&L[r * 72 + c16] = make_uint4(wbuf[0], wbuf[1], wbuf[2], wbuf[3]);
    *(uint4*)&L[r * 72 + c16 + 8] = make_uint4(wbuf[4], wbuf[5], wbuf[6], wbuf[7]);
    if (dA) {
      *(uint4*)&dA[0] = make_uint4(wbuf[0], wbuf[1], wbuf[2], wbuf[3]);
      *(uint4*)&dA[8] = make_uint4(wbuf[4], wbuf[5], wbuf[6], wbuf[7]);
    }
    __syncthreads();
    const int q = (t & 3) * 16;
    unsigned ow[8];
#pragma unroll
    for (int i = 0; i < 8; ++i) {
      const unsigned lo = L[(q + 2 * i) * 72 + r];
      const unsigned hi = L[(q + 2 * i + 1) * 72 + r];
      ow[i] = lo | (hi << 16);
    }
    unsigned short* dT = dTbase + (size_t)r * UT_STRIDE + q;
    *(uint4*)&dT[0] = make_uint4(ow[0], ow[1], ow[2], ow[3]);
    *(uint4*)&dT[8] = make_uint4(ow[4], ow[5], ow[6], ow[7]);
    return;
  }

  // ---- pbuild: P = I + H + H^2/2 + H^3/6 + H^4/24, H = hW[m]; out = P^T ----
  const int m = bid - 768;
  unsigned short* bufPrev = S;             // [128][PP]  H^g rows
  unsigned short* bufHT = S + 128 * PP;    // [128][PP]  H^T rows; reused for P^T
  const int lane = t & 63, w = t >> 6;
  const int quad = lane >> 4, ln15 = lane & 15;
  const float* Wm = W + (size_t)m * 16384;
  const float h = 1.f / 16.f;
#pragma unroll
  for (int v = 0; v < 16; ++v) {
    const int idx = (v * 256 + t) * 4;  // coalesced
    const float4 val = *(const float4*)&Wm[idx];
    const int k = idx >> 7, c = idx & 127;
    const unsigned short h0 = f32_to_bf16_rn(val.x * h);
    const unsigned short h1 = f32_to_bf16_rn(val.y * h);
    const unsigned short h2 = f32_to_bf16_rn(val.z * h);
    const unsigned short h3 = f32_to_bf16_rn(val.w * h);
    *(uint2*)&bufPrev[k * PP + c] =
        make_uint2((unsigned)h0 | ((unsigned)h1 << 16), (unsigned)h2 | ((unsigned)h3 << 16));
    bufHT[(c + 0) * PP + k] = h0;
    bufHT[(c + 1) * PP + k] = h1;
    bufHT[(c + 2) * PP + k] = h2;
    bufHT[(c + 3) * PP + k] = h3;
  }
  __syncthreads();
  const int rbase = w * 32;
  f32x4 Pacc[2][8];
#pragma unroll
  for (int i = 0; i < 2; ++i)
#pragma unroll
    for (int j = 0; j < 8; ++j) Pacc[i][j] = (f32x4){0.f, 0.f, 0.f, 0.f};
  const float coef[3] = {0.5f, 1.f / 6.f, 1.f / 24.f};
  for (int g = 0; g < 3; ++g) {
    f32x4 C[2][8];
#pragma unroll
    for (int i = 0; i < 2; ++i)
#pragma unroll
      for (int j = 0; j < 8; ++j) C[i][j] = (f32x4){0.f, 0.f, 0.f, 0.f};
#pragma unroll
    for (int kc = 0; kc < 128; kc += 32) {
      bf16x8 aF[2], bF[8];
#pragma unroll
      for (int i = 0; i < 2; ++i)
        aF[i] = *(const bf16x8*)&bufPrev[(rbase + 16 * i + ln15) * PP + kc + quad * 8];
#pragma unroll
      for (int j = 0; j < 8; ++j)
        bF[j] = *(const bf16x8*)&bufHT[(16 * j + ln15) * PP + kc + quad * 8];
#pragma unroll
      for (int i = 0; i < 2; ++i)
#pragma unroll
        for (int j = 0; j < 8; ++j)
          C[i][j] = __builtin_amdgcn_mfma_f32_16x16x32_bf16(aF[i], bF[j], C[i][j], 0, 0, 0);
    }
#pragma unroll
    for (int i = 0; i < 2; ++i)
#pragma unroll
      for (int j = 0; j < 8; ++j)
#pragma unroll
        for (int r = 0; r < 4; ++r) Pacc[i][j][r] += coef[g] * C[i][j][r];
    if (g < 2) {
      __syncthreads();
#pragma unroll
      for (int i = 0; i < 2; ++i)
#pragma unroll
        for (int j = 0; j < 8; ++j)
#pragma unroll
          for (int r = 0; r < 4; ++r) {
            const int row = rbase + 16 * i + quad * 4 + r;
            const int col = 16 * j + ln15;
            bufPrev[row * PP + col] = f32_to_bf16_rn(C[i][j][r]);
          }
      __syncthreads();
    }
  }
  __syncthreads();
#pragma unroll
  for (int i = 0; i < 2; ++i)
#pragma unroll
    for (int j = 0; j < 8; ++j)
#pragma unroll
      for (int r = 0; r < 4; ++r) {
        const int row = rbase + 16 * i + quad * 4 + r;  // e
        const int col = 16 * j + ln15;                  // f
        const float v = Pacc[i][j][r] + h * Wm[row * 128 + col] + (row == col ? 1.f : 0.f);
        bufHT[col * PP + row] = f32_to_bf16_rn(v);      // P^T[f][e]
      }
  __syncthreads();
  unsigned short* Pm = PgT + (size_t)m * 16384;
#pragma unroll
  for (int v = 0; v < 8; ++v) {
    const int idx = (v * 256 + t) * 8;
    const int f = idx >> 7, e = idx & 127;
    *(uint4*)&Pm[idx] = *(const uint4*)&bufHT[f * PP + e];
  }
}

// ---------------------------------------------------------------------------
// K1: GFT via bf16 MFMA from pre-transposed inputs.
// grid (mt=4, b=8, ks=16), 256 thr. Tile 64m x 128e, K=64 per block.
// ---------------------------------------------------------------------------
__global__ __launch_bounds__(256) void k1_gft(const unsigned short* __restrict__ Ut,
                                              const unsigned short* __restrict__ xt,
                                              float* __restrict__ xftp) {
  __shared__ unsigned short As[64 * 72];   // A[m][k]
  __shared__ unsigned short Bs[128 * 72];  // B^T[e][k]
  const int mt = blockIdx.x, b = blockIdx.y, ks = blockIdx.z;
  const int m0 = mt * 64, i0 = ks * 64;
  const int tid = threadIdx.x, lane = tid & 63, w = tid >> 6;
  const int quad = lane >> 4, ln15 = lane & 15;
  {
    const int m = tid >> 2, kq = (tid & 3) * 16;
    const unsigned short* s = Ut + ((size_t)(b * M_ + m0 + m)) * UT_STRIDE + i0 + kq;
    *(uint4*)&As[m * 72 + kq] = *(const uint4*)&s[0];
    *(uint4*)&As[m * 72 + kq + 8] = *(const uint4*)&s[8];
  }
  {
    const int e = tid >> 1, kq = (tid & 1) * 32;
    const unsigned short* s = xt + ((size_t)(b * E_ + e)) * UT_STRIDE + i0 + kq;
#pragma unroll
    for (int u = 0; u < 4; ++u)
      *(uint4*)&Bs[e * 72 + kq + u * 8] = *(const uint4*)&s[u * 8];
  }
  __syncthreads();
  f32x4 acc[8];
#pragma unroll
  for (int j = 0; j < 8; ++j) acc[j] = (f32x4){0.f, 0.f, 0.f, 0.f};
#pragma unroll
  for (int kc = 0; kc < 2; ++kc) {
    const bf16x8 aF = *(const bf16x8*)&As[(w * 16 + ln15) * 72 + kc * 32 + quad * 8];
#pragma unroll
    for (int j = 0; j < 8; ++j) {
      const bf16x8 bF = *(const bf16x8*)&Bs[(16 * j + ln15) * 72 + kc * 32 + quad * 8];
      acc[j] = __builtin_amdgcn_mfma_f32_16x16x32_bf16(aF, bF, acc[j], 0, 0, 0);
    }
  }
  float* dst = xftp + ((size_t)(ks * M_ + m0 + w * 16) * B_ + b) * E_;
#pragma unroll
  for (int j = 0; j < 8; ++j)
#pragma unroll
    for (int r = 0; r < 4; ++r)
      dst[(size_t)(quad * 4 + r) * (B_ * E_) + 16 * j + ln15] = acc[j][r];
}

// ---------------------------------------------------------------------------
// k2_ode: 16-step y_{t+1} = y_t P via MFMA; sums 16 k1 partials.
// Pt padded to PP pitch (was 128: 16-way bank conflict on Bf staging reads).
// ---------------------------------------------------------------------------
__global__ __launch_bounds__(256) void k2_ode(const float* __restrict__ xftp,
                                              const unsigned short* __restrict__ PgT,
                                              unsigned short* __restrict__ Y) {
  __shared__ unsigned short Pt[128 * PP];  // [f][e] = P[e][f]
  __shared__ unsigned short ztb[2 * 16 * 136];
  const int m = blockIdx.x, tid = threadIdx.x;
  const int lane = tid & 63, w = tid >> 6, quad = lane >> 4, ln15 = lane & 15;
  const unsigned short* Pm = PgT + (size_t)m * 16384;
#pragma unroll
  for (int v = 0; v < 8; ++v) {
    const int idx = (v * 256 + tid) * 8;
    const int f = idx >> 7, e = idx & 127;
    *(uint4*)&Pt[f * PP + e] = *(const uint4*)&Pm[idx];
  }
  {
    const int b = tid >> 5, e0 = (tid & 31) * 4;
    float4 a = make_float4(0.f, 0.f, 0.f, 0.f);
#pragma unroll
    for (int ks = 0; ks < 16; ++ks) {
      const float4 v = *(const float4*)&xftp[(((size_t)ks * M_ + m) * B_ + b) * E_ + e0];
      a.x += v.x; a.y += v.y; a.z += v.z; a.w += v.w;
    }
    const unsigned short q0 = f32_to_bf16_rn(a.x), q1 = f32_to_bf16_rn(a.y);
    const unsigned short q2 = f32_to_bf16_rn(a.z), q3 = f32_to_bf16_rn(a.w);
    *(uint2*)&ztb[b * 136 + e0] =
        make_uint2((unsigned)q0 | ((unsigned)q1 << 16), (unsigned)q2 | ((unsigned)q3 << 16));
    for (int idx = 8 * 136 + tid; idx < 16 * 136; idx += 256) ztb[idx] = 0;
  }
  __syncthreads();
  bf16x8 Bf[2][4];
#pragma unroll
  for (int nt = 0; nt < 2; ++nt)
#pragma unroll
    for (int c4 = 0; c4 < 4; ++c4)
      Bf[nt][c4] = *(const bf16x8*)&Pt[(w * 32 + nt * 16 + ln15) * PP + c4 * 32 + quad * 8];

  int p = 0;
  for (int t = 0; t < T_; ++t) {
    const unsigned short* zr = &ztb[p * 2176];
    unsigned short* zw = &ztb[(1 - p) * 2176];
    bf16x8 aF[4];
#pragma unroll
    for (int c4 = 0; c4 < 4; ++c4)
      aF[c4] = *(const bf16x8*)&zr[ln15 * 136 + c4 * 32 + quad * 8];
    f32x4 acc[2];
    acc[0] = (f32x4){0.f, 0.f, 0.f, 0.f};
    acc[1] = (f32x4){0.f, 0.f, 0.f, 0.f};
#pragma unroll
    for (int c4 = 0; c4 < 4; ++c4) {
      acc[0] = __builtin_amdgcn_mfma_f32_16x16x32_bf16(aF[c4], Bf[0][c4], acc[0], 0, 0, 0);
      acc[1] = __builtin_amdgcn_mfma_f32_16x16x32_bf16(aF[c4], Bf[1][c4], acc[1], 0, 0, 0);
    }
#pragma unroll
    for (int nt = 0; nt < 2; ++nt)
#pragma unroll
      for (int r = 0; r < 4; ++r) {
        const int row = quad * 4 + r;
        const int e = w * 32 + nt * 16 + ln15;
        const unsigned short hv = f32_to_bf16_rn(acc[nt][r]);
        zw[row * 136 + e] = hv;
        if (row < 8) Y[(((size_t)row * M_ + m) << 11) + (t << 7) + e] = hv;
      }
    __syncthreads();
    p ^= 1;
  }
}

// ---------------------------------------------------------------------------
// K3: iGFT via MFMA, B-operand transposed from Y in-LDS (k_transY fused away).
// out[t][b][n][e] = sum_m Ubf[b][n][m] * Y[b][m][t*128+e]
// grid (t=16, nb=8, b=8), 256 thr, 128x128 C-tile, K=256 in 4 chunks of 64.
// Bs XOR-swizzle: blk' = kb ^ ((te>>3)&7) -> write ~4-way, read at b128 floor.
// ---------------------------------------------------------------------------
__global__ __launch_bounds__(256) void k3_igft(const unsigned short* __restrict__ Ubf,
                                               const unsigned short* __restrict__ Y,
                                               float* __restrict__ out) {
  __shared__ __align__(16) char smem[18432 + 16384];       // 34816 B
  unsigned short* As = (unsigned short*)smem;              // [128][72]
  unsigned short* Bs = (unsigned short*)(smem + 18432);    // [128][64] swizzled
  float* Cst = (float*)smem;                               // [32][132] f32 (16896 B, in As)
  const int tt = blockIdx.x, nb = blockIdx.y, b = blockIdx.z;
  const int n0 = nb * 128;
  const int tid = threadIdx.x, lane = tid & 63, w = tid >> 6;
  const int quad = lane >> 4, ln15 = lane & 15;
  const int hn = w >> 1, hv = w & 1;
  const unsigned short* Ua = Ubf + ((size_t)b * N_ + n0) * UB_STRIDE;
  const unsigned short* Ym = Y + ((size_t)b * M_) * 2048 + tt * 128;
  f32x4 acc[4][4];
#pragma unroll
  for (int i = 0; i < 4; ++i)
#pragma unroll
    for (int j = 0; j < 4; ++j) acc[i][j] = (f32x4){0.f, 0.f, 0.f, 0.f};
  for (int kc = 0; kc < 256; kc += 64) {
    __syncthreads();
#pragma unroll
    for (int p = 0; p < 4; ++p) {
      const int f = p * 256 + tid;
      const int r = f >> 3, u8 = (f & 7) * 8;
      *(uint4*)&As[r * 72 + u8] = *(const uint4*)&Ua[(size_t)r * UB_STRIDE + kc + u8];
    }
#pragma unroll
    for (int p = 0; p < 4; ++p) {
      const int f = p * 256 + tid;
      const int ml = f >> 4;         // local m 0..63
      const int te8 = (f & 15) * 8;  // te block
      const uint4 v = *(const uint4*)&Ym[(size_t)(kc + ml) * 2048 + te8];
      const unsigned short* sv = (const unsigned short*)&v;
      const int kb = ml >> 3, klo = ml & 7;
#pragma unroll
      for (int i = 0; i < 8; ++i) {
        const int te = te8 + i;
        const int blk = kb ^ ((te >> 3) & 7);
        Bs[te * 64 + blk * 8 + klo] = sv[i];
      }
    }
    __syncthreads();
#pragma unroll
    for (int kc2 = 0; kc2 < 2; ++kc2) {
      bf16x8 aF[4], bF[4];
#pragma unroll
      for (int i = 0; i < 4; ++i)
        aF[i] = *(const bf16x8*)&As[(hn * 64 + 16 * i + ln15) * 72 + kc2 * 32 + quad * 8];
#pragma unroll
      for (int j = 0; j < 4; ++j) {
        const int row = hv * 64 + 16 * j + ln15;
        const int blk = (kc2 * 4 + quad) ^ ((row >> 3) & 7);
        bF[j] = *(const bf16x8*)&Bs[row * 64 + blk * 8];
      }
#pragma unroll
      for (int i = 0; i < 4; ++i)
#pragma unroll
        for (int j = 0; j < 4; ++j)
          acc[i][j] = __builtin_amdgcn_mfma_f32_16x16x32_bf16(aF[i], bF[j], acc[i][j], 0, 0, 0);
    }
  }
  float* ob = out + ((size_t)tt * B_ + b) * N_ * E_ + (size_t)n0 * E_;
#pragma unroll
  for (int c = 0; c < 4; ++c) {
    __syncthreads();
    if (hn == (c >> 1)) {
#pragma unroll
      for (int ii = 0; ii < 2; ++ii) {
        const int i = 2 * (c & 1) + ii;
#pragma unroll
        for (int j = 0; j < 4; ++j)
#pragma unroll
          for (int r = 0; r < 4; ++r)
            Cst[(16 * ii + quad * 4 + r) * 132 + hv * 64 + 16 * j + ln15] = acc[i][j][r];
      }
    }
    __syncthreads();
#pragma unroll
    for (int v = 0; v < 4; ++v) {
      const int f = v * 256 + tid;
      const int lr = f >> 5, e4 = (f & 31) * 4;
      *(float4*)&ob[(size_t)(c * 32 + lr) * E_ + e4] = *(const float4*)&Cst[lr * 132 + e4];
    }
  }
}

extern "C" void kernel_launch(void* const* d_in, const int* in_sizes, int n_in,
                              void* d_out, int out_size, void* d_ws, size_t ws_size,
                              hipStream_t stream) {
  const float* x = (const float*)d_in[0];
  // d_in[1] = times: fixed grid (i+1)/16 -> h = 1/16 constant
  const float* U = (const float*)d_in[2];
  const float* W = (const float*)d_in[3];
  float* out = (float*)d_out;

  // Disjoint layout in the 256 MiB workspace (no aliasing).
  char* ws = (char*)d_ws;
  float* xftp = (float*)ws;                                        //  0..16 MiB [16][M][B][E] f32
  unsigned short* PgT = (unsigned short*)(ws + (16u << 20));       // 16..24 MiB [M][128][128] bf16 (P^T)
  unsigned short* Y = (unsigned short*)(ws + (24u << 20));         // 24..32 MiB [B][M][2048] bf16
  unsigned short* Ut = (unsigned short*)(ws + (32u << 20));        // 32..40 MiB [B][256][1088] bf16
  unsigned short* xt = (unsigned short*)(ws + (40u << 20));        // 40..44 MiB [B][128][1088] bf16
  unsigned short* Ubf = (unsigned short*)(ws + (44u << 20));       // 44..52 MiB [B][1024][272] bf16

  kprep<<<dim3(1024), 256, 0, stream>>>(U, x, W, Ubf, Ut, xt, PgT);
  k1_gft<<<dim3(4, B_, 16), 256, 0, stream>>>(Ut, xt, xftp);
  k2_ode<<<dim3(M_), 256, 0, stream>>>(xftp, PgT, Y);
  k3_igft<<<dim3(16, 8, B_), 256, 0, stream>>>(Ubf, Y, out);
}

// Round 3
// 157.798 us; speedup vs baseline: 1.0700x; 1.0106x over previous
//
#include <hip/hip_runtime.h>

#define B_ 8
#define N_ 1024
#define E_ 128
#define T_ 16
#define M_ 256

#define UT_STRIDE 1088   // Ut/xt row pad (shorts): 2176B, breaks pow2 channel/bank aliasing
#define UB_STRIDE 272    // Ubf row pad (shorts): 544B
#define PP 136           // P-tile LDS pitch (shorts) = 272B = 17x16B: aligned b128, 2-way banks

typedef __attribute__((ext_vector_type(8))) short bf16x8;
typedef __attribute__((ext_vector_type(4))) float f32x4;

__device__ __forceinline__ unsigned short f32_to_bf16_rn(float f) {
  unsigned u = __float_as_uint(f);
  u = (u + 0x7fffu + ((u >> 16) & 1u)) >> 16;
  return (unsigned short)u;
}

// ---------------------------------------------------------------------------
// kprep: fused {U-transpose tiles | x-transpose tiles | RK4 propagator build}.
// grid(1024): bid<512 U-tiles (mt 4 x nt 16 x b 8); bid<768 x-tiles (256:
// et 2 x it 16 x b 8); else pbuild m = bid-768.
// ---------------------------------------------------------------------------
__global__ __launch_bounds__(256) void kprep(const float* __restrict__ U,
                                             const float* __restrict__ x,
                                             const float* __restrict__ W,
                                             unsigned short* __restrict__ Ubf,
                                             unsigned short* __restrict__ Ut,
                                             unsigned short* __restrict__ xt,
                                             unsigned short* __restrict__ PgT) {
  __shared__ __align__(16) unsigned short S[2 * 128 * PP];  // 69632 B (2 blocks/CU)
  const int bid = blockIdx.x, t = threadIdx.x;

  if (bid < 768) {
    // ---- 64x64 f32->bf16 transpose tile (U or x) ----
    unsigned short* L = S;  // [64][72]
    const int r = t >> 2, c16 = (t & 3) * 16;
    const float* src;
    unsigned short* dA = nullptr;
    unsigned short* dTbase;
    if (bid < 512) {
      const int m0 = (bid & 3) * 64, n0 = ((bid >> 2) & 15) * 64, b = bid >> 6;
      src = U + ((size_t)(b * N_ + n0 + r)) * N_ + m0 + c16;
      dA = Ubf + ((size_t)(b * N_ + n0 + r)) * UB_STRIDE + m0 + c16;
      dTbase = Ut + ((size_t)(b * M_ + m0)) * UT_STRIDE + n0;
    } else {
      const int u = bid - 512;  // 0..255: et 2 x it 16 x b 8
      const int e0 = (u & 1) * 64, i0 = ((u >> 1) & 15) * 64, b = u >> 5;
      src = x + ((size_t)(b * N_ + i0 + r)) * E_ + e0 + c16;
      dTbase = xt + ((size_t)(b * E_ + e0)) * UT_STRIDE + i0;
    }
    unsigned wbuf[8];
#pragma unroll
    for (int u = 0; u < 4; ++u) {
      const float4 v = ((const float4*)src)[u];
      wbuf[2 * u + 0] = (unsigned)f32_to_bf16_rn(v.x) | ((unsigned)f32_to_bf16_rn(v.y) << 16);
      wbuf[2 * u + 1] = (unsigned)f32_to_bf16_rn(v.z) | ((unsigned)f32_to_bf16_rn(v.w) << 16);
    }
    *(uint4*)&L[r * 72 + c16] = make_uint4(wbuf[0], wbuf[1], wbuf[2], wbuf[3]);
    *(uint4*)&L[r * 72 + c16 + 8] = make_uint4(wbuf[4], wbuf[5], wbuf[6], wbuf[7]);
    if (dA) {
      *(uint4*)&dA[0] = make_uint4(wbuf[0], wbuf[1], wbuf[2], wbuf[3]);
      *(uint4*)&dA[8] = make_uint4(wbuf[4], wbuf[5], wbuf[6], wbuf[7]);
    }
    __syncthreads();
    const int q = (t & 3) * 16;
    unsigned ow[8];
#pragma unroll
    for (int i = 0; i < 8; ++i) {
      const unsigned lo = L[(q + 2 * i) * 72 + r];
      const unsigned hi = L[(q + 2 * i + 1) * 72 + r];
      ow[i] = lo | (hi << 16);
    }
    unsigned short* dT = dTbase + (size_t)r * UT_STRIDE + q;
    *(uint4*)&dT[0] = make_uint4(ow[0], ow[1], ow[2], ow[3]);
    *(uint4*)&dT[8] = make_uint4(ow[4], ow[5], ow[6], ow[7]);
    return;
  }

  // ---- pbuild: P = I + H + H^2/2 + H^3/6 + H^4/24, H = hW[m]; out = P^T ----
  const int m = bid - 768;
  unsigned short* bufPrev = S;             // [128][PP]  H^g rows
  unsigned short* bufHT = S + 128 * PP;    // [128][PP]  H^T rows; reused for P^T
  const int lane = t & 63, w = t >> 6;
  const int quad = lane >> 4, ln15 = lane & 15;
  const float* Wm = W + (size_t)m * 16384;
  const float h = 1.f / 16.f;
#pragma unroll
  for (int v = 0; v < 16; ++v) {
    const int idx = (v * 256 + t) * 4;  // coalesced
    const float4 val = *(const float4*)&Wm[idx];
    const int k = idx >> 7, c = idx & 127;
    const unsigned short h0 = f32_to_bf16_rn(val.x * h);
    const unsigned short h1 = f32_to_bf16_rn(val.y * h);
    const unsigned short h2 = f32_to_bf16_rn(val.z * h);
    const unsigned short h3 = f32_to_bf16_rn(val.w * h);
    *(uint2*)&bufPrev[k * PP + c] =
        make_uint2((unsigned)h0 | ((unsigned)h1 << 16), (unsigned)h2 | ((unsigned)h3 << 16));
    bufHT[(c + 0) * PP + k] = h0;
    bufHT[(c + 1) * PP + k] = h1;
    bufHT[(c + 2) * PP + k] = h2;
    bufHT[(c + 3) * PP + k] = h3;
  }
  __syncthreads();
  const int rbase = w * 32;
  f32x4 Pacc[2][8];
#pragma unroll
  for (int i = 0; i < 2; ++i)
#pragma unroll
    for (int j = 0; j < 8; ++j) Pacc[i][j] = (f32x4){0.f, 0.f, 0.f, 0.f};
  const float coef[3] = {0.5f, 1.f / 6.f, 1.f / 24.f};
  for (int g = 0; g < 3; ++g) {
    f32x4 C[2][8];
#pragma unroll
    for (int i = 0; i < 2; ++i)
#pragma unroll
      for (int j = 0; j < 8; ++j) C[i][j] = (f32x4){0.f, 0.f, 0.f, 0.f};
#pragma unroll
    for (int kc = 0; kc < 128; kc += 32) {
      bf16x8 aF[2], bF[8];
#pragma unroll
      for (int i = 0; i < 2; ++i)
        aF[i] = *(const bf16x8*)&bufPrev[(rbase + 16 * i + ln15) * PP + kc + quad * 8];
#pragma unroll
      for (int j = 0; j < 8; ++j)
        bF[j] = *(const bf16x8*)&bufHT[(16 * j + ln15) * PP + kc + quad * 8];
#pragma unroll
      for (int i = 0; i < 2; ++i)
#pragma unroll
        for (int j = 0; j < 8; ++j)
          C[i][j] = __builtin_amdgcn_mfma_f32_16x16x32_bf16(aF[i], bF[j], C[i][j], 0, 0, 0);
    }
#pragma unroll
    for (int i = 0; i < 2; ++i)
#pragma unroll
      for (int j = 0; j < 8; ++j)
#pragma unroll
        for (int r = 0; r < 4; ++r) Pacc[i][j][r] += coef[g] * C[i][j][r];
    if (g < 2) {
      __syncthreads();
#pragma unroll
      for (int i = 0; i < 2; ++i)
#pragma unroll
        for (int j = 0; j < 8; ++j)
#pragma unroll
          for (int r = 0; r < 4; ++r) {
            const int row = rbase + 16 * i + quad * 4 + r;
            const int col = 16 * j + ln15;
            bufPrev[row * PP + col] = f32_to_bf16_rn(C[i][j][r]);
          }
      __syncthreads();
    }
  }
  __syncthreads();
#pragma unroll
  for (int i = 0; i < 2; ++i)
#pragma unroll
    for (int j = 0; j < 8; ++j)
#pragma unroll
      for (int r = 0; r < 4; ++r) {
        const int row = rbase + 16 * i + quad * 4 + r;  // e
        const int col = 16 * j + ln15;                  // f
        const float v = Pacc[i][j][r] + h * Wm[row * 128 + col] + (row == col ? 1.f : 0.f);
        bufHT[col * PP + row] = f32_to_bf16_rn(v);      // P^T[f][e]
      }
  __syncthreads();
  unsigned short* Pm = PgT + (size_t)m * 16384;
#pragma unroll
  for (int v = 0; v < 8; ++v) {
    const int idx = (v * 256 + t) * 8;
    const int f = idx >> 7, e = idx & 127;
    *(uint4*)&Pm[idx] = *(const uint4*)&bufHT[f * PP + e];
  }
}

// ---------------------------------------------------------------------------
// K1: GFT via bf16 MFMA from pre-transposed inputs.
// grid (mt=4, b=8, ks=16), 256 thr. Tile 64m x 128e, K=64 per block.
// ---------------------------------------------------------------------------
__global__ __launch_bounds__(256) void k1_gft(const unsigned short* __restrict__ Ut,
                                              const unsigned short* __restrict__ xt,
                                              float* __restrict__ xftp) {
  __shared__ unsigned short As[64 * 72];   // A[m][k]
  __shared__ unsigned short Bs[128 * 72];  // B^T[e][k]
  const int mt = blockIdx.x, b = blockIdx.y, ks = blockIdx.z;
  const int m0 = mt * 64, i0 = ks * 64;
  const int tid = threadIdx.x, lane = tid & 63, w = tid >> 6;
  const int quad = lane >> 4, ln15 = lane & 15;
  {
    const int m = tid >> 2, kq = (tid & 3) * 16;
    const unsigned short* s = Ut + ((size_t)(b * M_ + m0 + m)) * UT_STRIDE + i0 + kq;
    *(uint4*)&As[m * 72 + kq] = *(const uint4*)&s[0];
    *(uint4*)&As[m * 72 + kq + 8] = *(const uint4*)&s[8];
  }
  {
    const int e = tid >> 1, kq = (tid & 1) * 32;
    const unsigned short* s = xt + ((size_t)(b * E_ + e)) * UT_STRIDE + i0 + kq;
#pragma unroll
    for (int u = 0; u < 4; ++u)
      *(uint4*)&Bs[e * 72 + kq + u * 8] = *(const uint4*)&s[u * 8];
  }
  __syncthreads();
  f32x4 acc[8];
#pragma unroll
  for (int j = 0; j < 8; ++j) acc[j] = (f32x4){0.f, 0.f, 0.f, 0.f};
#pragma unroll
  for (int kc = 0; kc < 2; ++kc) {
    const bf16x8 aF = *(const bf16x8*)&As[(w * 16 + ln15) * 72 + kc * 32 + quad * 8];
#pragma unroll
    for (int j = 0; j < 8; ++j) {
      const bf16x8 bF = *(const bf16x8*)&Bs[(16 * j + ln15) * 72 + kc * 32 + quad * 8];
      acc[j] = __builtin_amdgcn_mfma_f32_16x16x32_bf16(aF, bF, acc[j], 0, 0, 0);
    }
  }
  float* dst = xftp + ((size_t)(ks * M_ + m0 + w * 16) * B_ + b) * E_;
#pragma unroll
  for (int j = 0; j < 8; ++j)
#pragma unroll
    for (int r = 0; r < 4; ++r)
      dst[(size_t)(quad * 4 + r) * (B_ * E_) + 16 * j + ln15] = acc[j][r];
}

// ---------------------------------------------------------------------------
// k2_ode: 16-step y_{t+1} = y_t P via MFMA; sums 16 k1 partials.
// ---------------------------------------------------------------------------
__global__ __launch_bounds__(256) void k2_ode(const float* __restrict__ xftp,
                                              const unsigned short* __restrict__ PgT,
                                              unsigned short* __restrict__ Y) {
  __shared__ unsigned short Pt[128 * PP];  // [f][e] = P[e][f]
  __shared__ unsigned short ztb[2 * 16 * 136];
  const int m = blockIdx.x, tid = threadIdx.x;
  const int lane = tid & 63, w = tid >> 6, quad = lane >> 4, ln15 = lane & 15;
  const unsigned short* Pm = PgT + (size_t)m * 16384;
#pragma unroll
  for (int v = 0; v < 8; ++v) {
    const int idx = (v * 256 + tid) * 8;
    const int f = idx >> 7, e = idx & 127;
    *(uint4*)&Pt[f * PP + e] = *(const uint4*)&Pm[idx];
  }
  {
    const int b = tid >> 5, e0 = (tid & 31) * 4;
    float4 a = make_float4(0.f, 0.f, 0.f, 0.f);
#pragma unroll
    for (int ks = 0; ks < 16; ++ks) {
      const float4 v = *(const float4*)&xftp[(((size_t)ks * M_ + m) * B_ + b) * E_ + e0];
      a.x += v.x; a.y += v.y; a.z += v.z; a.w += v.w;
    }
    const unsigned short q0 = f32_to_bf16_rn(a.x), q1 = f32_to_bf16_rn(a.y);
    const unsigned short q2 = f32_to_bf16_rn(a.z), q3 = f32_to_bf16_rn(a.w);
    *(uint2*)&ztb[b * 136 + e0] =
        make_uint2((unsigned)q0 | ((unsigned)q1 << 16), (unsigned)q2 | ((unsigned)q3 << 16));
    for (int idx = 8 * 136 + tid; idx < 16 * 136; idx += 256) ztb[idx] = 0;
  }
  __syncthreads();
  bf16x8 Bf[2][4];
#pragma unroll
  for (int nt = 0; nt < 2; ++nt)
#pragma unroll
    for (int c4 = 0; c4 < 4; ++c4)
      Bf[nt][c4] = *(const bf16x8*)&Pt[(w * 32 + nt * 16 + ln15) * PP + c4 * 32 + quad * 8];

  int p = 0;
  for (int t = 0; t < T_; ++t) {
    const unsigned short* zr = &ztb[p * 2176];
    unsigned short* zw = &ztb[(1 - p) * 2176];
    bf16x8 aF[4];
#pragma unroll
    for (int c4 = 0; c4 < 4; ++c4)
      aF[c4] = *(const bf16x8*)&zr[ln15 * 136 + c4 * 32 + quad * 8];
    f32x4 acc[2];
    acc[0] = (f32x4){0.f, 0.f, 0.f, 0.f};
    acc[1] = (f32x4){0.f, 0.f, 0.f, 0.f};
#pragma unroll
    for (int c4 = 0; c4 < 4; ++c4) {
      acc[0] = __builtin_amdgcn_mfma_f32_16x16x32_bf16(aF[c4], Bf[0][c4], acc[0], 0, 0, 0);
      acc[1] = __builtin_amdgcn_mfma_f32_16x16x32_bf16(aF[c4], Bf[1][c4], acc[1], 0, 0, 0);
    }
#pragma unroll
    for (int nt = 0; nt < 2; ++nt)
#pragma unroll
      for (int r = 0; r < 4; ++r) {
        const int row = quad * 4 + r;
        const int e = w * 32 + nt * 16 + ln15;
        const unsigned short hv = f32_to_bf16_rn(acc[nt][r]);
        zw[row * 136 + e] = hv;
        if (row < 8) Y[(((size_t)row * M_ + m) << 11) + (t << 7) + e] = hv;
      }
    __syncthreads();
    p ^= 1;
  }
}

// ---------------------------------------------------------------------------
// K3: iGFT via MFMA, B-operand transposed from Y in-LDS.
// out[t][b][n][e] = sum_m Ubf[b][n][m] * Y[b][m][t*128+e]
// grid (t=16, nb=8, b=8), 256 thr, 128x128 C-tile, K=256 in 4 chunks of 64.
// Bs dual-XOR swizzle: blk = kb ^ ((te>>3)&7) ^ (te&7). Bank = f(blk) only
// (128B rows wrap banks exactly): write ~2-way, read at exact b128 floor.
// Old (te>>3)-only read swizzle was 8-way-conflicted on ds_read_b128.
// Epilogue: direct f32 scatter stores (L2 write-back coalesces); Cst LDS
// round-trip + 8 barriers deleted.
// ---------------------------------------------------------------------------
__global__ __launch_bounds__(256) void k3_igft(const unsigned short* __restrict__ Ubf,
                                               const unsigned short* __restrict__ Y,
                                               float* __restrict__ out) {
  __shared__ __align__(16) char smem[18432 + 16384];       // 34816 B
  unsigned short* As = (unsigned short*)smem;              // [128][72]
  unsigned short* Bs = (unsigned short*)(smem + 18432);    // [128][64] swizzled
  const int tt = blockIdx.x, nb = blockIdx.y, b = blockIdx.z;
  const int n0 = nb * 128;
  const int tid = threadIdx.x, lane = tid & 63, w = tid >> 6;
  const int quad = lane >> 4, ln15 = lane & 15;
  const int hn = w >> 1, hv = w & 1;
  const unsigned short* Ua = Ubf + ((size_t)b * N_ + n0) * UB_STRIDE;
  const unsigned short* Ym = Y + ((size_t)b * M_) * 2048 + tt * 128;
  f32x4 acc[4][4];
#pragma unroll
  for (int i = 0; i < 4; ++i)
#pragma unroll
    for (int j = 0; j < 4; ++j) acc[i][j] = (f32x4){0.f, 0.f, 0.f, 0.f};
  for (int kc = 0; kc < 256; kc += 64) {
    __syncthreads();
#pragma unroll
    for (int p = 0; p < 4; ++p) {
      const int f = p * 256 + tid;
      const int r = f >> 3, u8 = (f & 7) * 8;
      *(uint4*)&As[r * 72 + u8] = *(const uint4*)&Ua[(size_t)r * UB_STRIDE + kc + u8];
    }
#pragma unroll
    for (int p = 0; p < 4; ++p) {
      const int f = p * 256 + tid;
      const int ml = f >> 4;         // local m 0..63
      const int te8 = (f & 15) * 8;  // te block
      const uint4 v = *(const uint4*)&Ym[(size_t)(kc + ml) * 2048 + te8];
      const unsigned short* sv = (const unsigned short*)&v;
      const int kb = ml >> 3, klo = ml & 7;
#pragma unroll
      for (int i = 0; i < 8; ++i) {
        const int te = te8 + i;
        const int blk = kb ^ ((te >> 3) & 7) ^ (te & 7);
        Bs[te * 64 + blk * 8 + klo] = sv[i];
      }
    }
    __syncthreads();
#pragma unroll
    for (int kc2 = 0; kc2 < 2; ++kc2) {
      bf16x8 aF[4], bF[4];
#pragma unroll
      for (int i = 0; i < 4; ++i)
        aF[i] = *(const bf16x8*)&As[(hn * 64 + 16 * i + ln15) * 72 + kc2 * 32 + quad * 8];
#pragma unroll
      for (int j = 0; j < 4; ++j) {
        const int row = hv * 64 + 16 * j + ln15;
        const int blk = (kc2 * 4 + quad) ^ ((row >> 3) & 7) ^ (row & 7);
        bF[j] = *(const bf16x8*)&Bs[row * 64 + blk * 8];
      }
#pragma unroll
      for (int i = 0; i < 4; ++i)
#pragma unroll
        for (int j = 0; j < 4; ++j)
          acc[i][j] = __builtin_amdgcn_mfma_f32_16x16x32_bf16(aF[i], bF[j], acc[i][j], 0, 0, 0);
    }
  }
  // direct C scatter: per store instr, 4 x 64B segments; r-unroll fills rows
  float* ob = out + ((size_t)tt * B_ + b) * N_ * E_ + (size_t)n0 * E_;
#pragma unroll
  for (int i = 0; i < 4; ++i)
#pragma unroll
    for (int j = 0; j < 4; ++j)
#pragma unroll
      for (int r = 0; r < 4; ++r) {
        const int n = hn * 64 + 16 * i + quad * 4 + r;
        const int e = hv * 64 + 16 * j + ln15;
        ob[(size_t)n * E_ + e] = acc[i][j][r];
      }
}

extern "C" void kernel_launch(void* const* d_in, const int* in_sizes, int n_in,
                              void* d_out, int out_size, void* d_ws, size_t ws_size,
                              hipStream_t stream) {
  const float* x = (const float*)d_in[0];
  // d_in[1] = times: fixed grid (i+1)/16 -> h = 1/16 constant
  const float* U = (const float*)d_in[2];
  const float* W = (const float*)d_in[3];
  float* out = (float*)d_out;

  // Disjoint layout in the 256 MiB workspace (no aliasing).
  char* ws = (char*)d_ws;
  float* xftp = (float*)ws;                                        //  0..16 MiB [16][M][B][E] f32
  unsigned short* PgT = (unsigned short*)(ws + (16u << 20));       // 16..24 MiB [M][128][128] bf16 (P^T)
  unsigned short* Y = (unsigned short*)(ws + (24u << 20));         // 24..32 MiB [B][M][2048] bf16
  unsigned short* Ut = (unsigned short*)(ws + (32u << 20));        // 32..40 MiB [B][256][1088] bf16
  unsigned short* xt = (unsigned short*)(ws + (40u << 20));        // 40..44 MiB [B][128][1088] bf16
  unsigned short* Ubf = (unsigned short*)(ws + (44u << 20));       // 44..52 MiB [B][1024][272] bf16

  kprep<<<dim3(1024), 256, 0, stream>>>(U, x, W, Ubf, Ut, xt, PgT);
  k1_gft<<<dim3(4, B_, 16), 256, 0, stream>>>(Ut, xt, xftp);
  k2_ode<<<dim3(M_), 256, 0, stream>>>(xftp, PgT, Y);
  k3_igft<<<dim3(16, 8, B_), 256, 0, stream>>>(Ubf, Y, out);
}

// Round 4
// 154.763 us; speedup vs baseline: 1.0909x; 1.0196x over previous
//
#include <hip/hip_runtime.h>

#define B_ 8
#define N_ 1024
#define E_ 128
#define T_ 16
#define M_ 256

#define UT_STRIDE 1088   // Ut/xt row pad (shorts): 2176B, breaks pow2 channel/bank aliasing
#define UB_STRIDE 272    // Ubf row pad (shorts): 544B
#define PP 136           // P-tile LDS pitch (shorts) = 272B = 17x16B: aligned b128, 2-way banks
#define KS_ 8            // k1 K-split: 8 partials of K=128

typedef __attribute__((ext_vector_type(8))) short bf16x8;
typedef __attribute__((ext_vector_type(4))) float f32x4;

__device__ __forceinline__ unsigned short f32_to_bf16_rn(float f) {
  unsigned u = __float_as_uint(f);
  u = (u + 0x7fffu + ((u >> 16) & 1u)) >> 16;
  return (unsigned short)u;
}

// ---------------------------------------------------------------------------
// kprep: fused {U-transpose tiles | x-transpose tiles | RK4 propagator build}.
// grid(1024): bid<512 U-tiles (mt 4 x nt 16 x b 8); bid<768 x-tiles (256:
// et 2 x it 16 x b 8); else pbuild m = bid-768.
// ---------------------------------------------------------------------------
__global__ __launch_bounds__(256) void kprep(const float* __restrict__ U,
                                             const float* __restrict__ x,
                                             const float* __restrict__ W,
                                             unsigned short* __restrict__ Ubf,
                                             unsigned short* __restrict__ Ut,
                                             unsigned short* __restrict__ xt,
                                             unsigned short* __restrict__ PgT) {
  __shared__ __align__(16) unsigned short S[2 * 128 * PP];  // 69632 B (2 blocks/CU)
  const int bid = blockIdx.x, t = threadIdx.x;

  if (bid < 768) {
    // ---- 64x64 f32->bf16 transpose tile (U or x) ----
    unsigned short* L = S;  // [64][72]
    const int r = t >> 2, c16 = (t & 3) * 16;
    const float* src;
    unsigned short* dA = nullptr;
    unsigned short* dTbase;
    if (bid < 512) {
      const int m0 = (bid & 3) * 64, n0 = ((bid >> 2) & 15) * 64, b = bid >> 6;
      src = U + ((size_t)(b * N_ + n0 + r)) * N_ + m0 + c16;
      dA = Ubf + ((size_t)(b * N_ + n0 + r)) * UB_STRIDE + m0 + c16;
      dTbase = Ut + ((size_t)(b * M_ + m0)) * UT_STRIDE + n0;
    } else {
      const int u = bid - 512;  // 0..255: et 2 x it 16 x b 8
      const int e0 = (u & 1) * 64, i0 = ((u >> 1) & 15) * 64, b = u >> 5;
      src = x + ((size_t)(b * N_ + i0 + r)) * E_ + e0 + c16;
      dTbase = xt + ((size_t)(b * E_ + e0)) * UT_STRIDE + i0;
    }
    unsigned wbuf[8];
#pragma unroll
    for (int u = 0; u < 4; ++u) {
      const float4 v = ((const float4*)src)[u];
      wbuf[2 * u + 0] = (unsigned)f32_to_bf16_rn(v.x) | ((unsigned)f32_to_bf16_rn(v.y) << 16);
      wbuf[2 * u + 1] = (unsigned)f32_to_bf16_rn(v.z) | ((unsigned)f32_to_bf16_rn(v.w) << 16);
    }
    *(uint4*)&L[r * 72 + c16] = make_uint4(wbuf[0], wbuf[1], wbuf[2], wbuf[3]);
    *(uint4*)&L[r * 72 + c16 + 8] = make_uint4(wbuf[4], wbuf[5], wbuf[6], wbuf[7]);
    if (dA) {
      *(uint4*)&dA[0] = make_uint4(wbuf[0], wbuf[1], wbuf[2], wbuf[3]);
      *(uint4*)&dA[8] = make_uint4(wbuf[4], wbuf[5], wbuf[6], wbuf[7]);
    }
    __syncthreads();
    const int q = (t & 3) * 16;
    unsigned ow[8];
#pragma unroll
    for (int i = 0; i < 8; ++i) {
      const unsigned lo = L[(q + 2 * i) * 72 + r];
      const unsigned hi = L[(q + 2 * i + 1) * 72 + r];
      ow[i] = lo | (hi << 16);
    }
    unsigned short* dT = dTbase + (size_t)r * UT_STRIDE + q;
    *(uint4*)&dT[0] = make_uint4(ow[0], ow[1], ow[2], ow[3]);
    *(uint4*)&dT[8] = make_uint4(ow[4], ow[5], ow[6], ow[7]);
    return;
  }

  // ---- pbuild: P = I + H + H^2/2 + H^3/6 + H^4/24, H = hW[m]; out = P^T ----
  const int m = bid - 768;
  unsigned short* bufPrev = S;             // [128][PP]  H^g rows
  unsigned short* bufHT = S + 128 * PP;    // [128][PP]  H^T rows; reused for P^T
  const int lane = t & 63, w = t >> 6;
  const int quad = lane >> 4, ln15 = lane & 15;
  const float* Wm = W + (size_t)m * 16384;
  const float h = 1.f / 16.f;
#pragma unroll
  for (int v = 0; v < 16; ++v) {
    const int idx = (v * 256 + t) * 4;  // coalesced
    const float4 val = *(const float4*)&Wm[idx];
    const int k = idx >> 7, c = idx & 127;
    const unsigned short h0 = f32_to_bf16_rn(val.x * h);
    const unsigned short h1 = f32_to_bf16_rn(val.y * h);
    const unsigned short h2 = f32_to_bf16_rn(val.z * h);
    const unsigned short h3 = f32_to_bf16_rn(val.w * h);
    *(uint2*)&bufPrev[k * PP + c] =
        make_uint2((unsigned)h0 | ((unsigned)h1 << 16), (unsigned)h2 | ((unsigned)h3 << 16));
    bufHT[(c + 0) * PP + k] = h0;
    bufHT[(c + 1) * PP + k] = h1;
    bufHT[(c + 2) * PP + k] = h2;
    bufHT[(c + 3) * PP + k] = h3;
  }
  __syncthreads();
  const int rbase = w * 32;
  f32x4 Pacc[2][8];
#pragma unroll
  for (int i = 0; i < 2; ++i)
#pragma unroll
    for (int j = 0; j < 8; ++j) Pacc[i][j] = (f32x4){0.f, 0.f, 0.f, 0.f};
  const float coef[3] = {0.5f, 1.f / 6.f, 1.f / 24.f};
  for (int g = 0; g < 3; ++g) {
    f32x4 C[2][8];
#pragma unroll
    for (int i = 0; i < 2; ++i)
#pragma unroll
      for (int j = 0; j < 8; ++j) C[i][j] = (f32x4){0.f, 0.f, 0.f, 0.f};
#pragma unroll
    for (int kc = 0; kc < 128; kc += 32) {
      bf16x8 aF[2], bF[8];
#pragma unroll
      for (int i = 0; i < 2; ++i)
        aF[i] = *(const bf16x8*)&bufPrev[(rbase + 16 * i + ln15) * PP + kc + quad * 8];
#pragma unroll
      for (int j = 0; j < 8; ++j)
        bF[j] = *(const bf16x8*)&bufHT[(16 * j + ln15) * PP + kc + quad * 8];
#pragma unroll
      for (int i = 0; i < 2; ++i)
#pragma unroll
        for (int j = 0; j < 8; ++j)
          C[i][j] = __builtin_amdgcn_mfma_f32_16x16x32_bf16(aF[i], bF[j], C[i][j], 0, 0, 0);
    }
#pragma unroll
    for (int i = 0; i < 2; ++i)
#pragma unroll
      for (int j = 0; j < 8; ++j)
#pragma unroll
        for (int r = 0; r < 4; ++r) Pacc[i][j][r] += coef[g] * C[i][j][r];
    if (g < 2) {
      __syncthreads();
#pragma unroll
      for (int i = 0; i < 2; ++i)
#pragma unroll
        for (int j = 0; j < 8; ++j)
#pragma unroll
          for (int r = 0; r < 4; ++r) {
            const int row = rbase + 16 * i + quad * 4 + r;
            const int col = 16 * j + ln15;
            bufPrev[row * PP + col] = f32_to_bf16_rn(C[i][j][r]);
          }
      __syncthreads();
    }
  }
  __syncthreads();
#pragma unroll
  for (int i = 0; i < 2; ++i)
#pragma unroll
    for (int j = 0; j < 8; ++j)
#pragma unroll
      for (int r = 0; r < 4; ++r) {
        const int row = rbase + 16 * i + quad * 4 + r;  // e
        const int col = 16 * j + ln15;                  // f
        const float v = Pacc[i][j][r] + h * Wm[row * 128 + col] + (row == col ? 1.f : 0.f);
        bufHT[col * PP + row] = f32_to_bf16_rn(v);      // P^T[f][e]
      }
  __syncthreads();
  unsigned short* Pm = PgT + (size_t)m * 16384;
#pragma unroll
  for (int v = 0; v < 8; ++v) {
    const int idx = (v * 256 + t) * 8;
    const int f = idx >> 7, e = idx & 127;
    *(uint4*)&Pm[idx] = *(const uint4*)&bufHT[f * PP + e];
  }
}

// ---------------------------------------------------------------------------
// K1: GFT via bf16 MFMA. 1-D grid(256), XCD-pinned: b = bid%8 so all blocks
// sharing Ut[b]/xt[b] land on one XCD's L2 (T1 heuristic; perf-only).
// Each block: K=128 (2 staged 64-K sub-tiles), tile 64m x 128e.
// xftp shrinks [16]->[8] partials: -16 MB round-trip traffic vs ks=16.
// ---------------------------------------------------------------------------
__global__ __launch_bounds__(256) void k1_gft(const unsigned short* __restrict__ Ut,
                                              const unsigned short* __restrict__ xt,
                                              float* __restrict__ xftp) {
  __shared__ unsigned short As[64 * 72];   // A[m][k]
  __shared__ unsigned short Bs[128 * 72];  // B^T[e][k]
  const int f = blockIdx.x;
  const int b = f & 7, rr = f >> 3;
  const int mt = rr & 3, ko = rr >> 2;     // ko 0..7
  const int m0 = mt * 64;
  const int tid = threadIdx.x, lane = tid & 63, w = tid >> 6;
  const int quad = lane >> 4, ln15 = lane & 15;
  f32x4 acc[8];
#pragma unroll
  for (int j = 0; j < 8; ++j) acc[j] = (f32x4){0.f, 0.f, 0.f, 0.f};
#pragma unroll
  for (int s = 0; s < 2; ++s) {
    const int i0 = (ko * 2 + s) * 64;
    if (s) __syncthreads();  // LDS reuse guard
    {
      const int m = tid >> 2, kq = (tid & 3) * 16;
      const unsigned short* sp = Ut + ((size_t)(b * M_ + m0 + m)) * UT_STRIDE + i0 + kq;
      *(uint4*)&As[m * 72 + kq] = *(const uint4*)&sp[0];
      *(uint4*)&As[m * 72 + kq + 8] = *(const uint4*)&sp[8];
    }
    {
      const int e = tid >> 1, kq = (tid & 1) * 32;
      const unsigned short* sp = xt + ((size_t)(b * E_ + e)) * UT_STRIDE + i0 + kq;
#pragma unroll
      for (int u = 0; u < 4; ++u)
        *(uint4*)&Bs[e * 72 + kq + u * 8] = *(const uint4*)&sp[u * 8];
    }
    __syncthreads();
#pragma unroll
    for (int kc = 0; kc < 2; ++kc) {
      const bf16x8 aF = *(const bf16x8*)&As[(w * 16 + ln15) * 72 + kc * 32 + quad * 8];
#pragma unroll
      for (int j = 0; j < 8; ++j) {
        const bf16x8 bF = *(const bf16x8*)&Bs[(16 * j + ln15) * 72 + kc * 32 + quad * 8];
        acc[j] = __builtin_amdgcn_mfma_f32_16x16x32_bf16(aF, bF, acc[j], 0, 0, 0);
      }
    }
  }
  float* dst = xftp + ((size_t)(ko * M_ + m0 + w * 16) * B_ + b) * E_;
#pragma unroll
  for (int j = 0; j < 8; ++j)
#pragma unroll
    for (int r = 0; r < 4; ++r)
      dst[(size_t)(quad * 4 + r) * (B_ * E_) + 16 * j + ln15] = acc[j][r];
}

// ---------------------------------------------------------------------------
// k2_ode: 16-step y_{t+1} = y_t P via MFMA; sums KS_=8 k1 partials.
// block m reads PgT[m] written by kprep block 768+m: both (768+m)%8 == m%8
// -> same XCD, likely L2-resident (accidental producer/consumer alignment).
// ---------------------------------------------------------------------------
__global__ __launch_bounds__(256) void k2_ode(const float* __restrict__ xftp,
                                              const unsigned short* __restrict__ PgT,
                                              unsigned short* __restrict__ Y) {
  __shared__ unsigned short Pt[128 * PP];  // [f][e] = P[e][f]
  __shared__ unsigned short ztb[2 * 16 * 136];
  const int m = blockIdx.x, tid = threadIdx.x;
  const int lane = tid & 63, w = tid >> 6, quad = lane >> 4, ln15 = lane & 15;
  const unsigned short* Pm = PgT + (size_t)m * 16384;
#pragma unroll
  for (int v = 0; v < 8; ++v) {
    const int idx = (v * 256 + tid) * 8;
    const int f = idx >> 7, e = idx & 127;
    *(uint4*)&Pt[f * PP + e] = *(const uint4*)&Pm[idx];
  }
  {
    const int b = tid >> 5, e0 = (tid & 31) * 4;
    float4 a = make_float4(0.f, 0.f, 0.f, 0.f);
#pragma unroll
    for (int ks = 0; ks < KS_; ++ks) {
      const float4 v = *(const float4*)&xftp[(((size_t)ks * M_ + m) * B_ + b) * E_ + e0];
      a.x += v.x; a.y += v.y; a.z += v.z; a.w += v.w;
    }
    const unsigned short q0 = f32_to_bf16_rn(a.x), q1 = f32_to_bf16_rn(a.y);
    const unsigned short q2 = f32_to_bf16_rn(a.z), q3 = f32_to_bf16_rn(a.w);
    *(uint2*)&ztb[b * 136 + e0] =
        make_uint2((unsigned)q0 | ((unsigned)q1 << 16), (unsigned)q2 | ((unsigned)q3 << 16));
    for (int idx = 8 * 136 + tid; idx < 16 * 136; idx += 256) ztb[idx] = 0;
  }
  __syncthreads();
  bf16x8 Bf[2][4];
#pragma unroll
  for (int nt = 0; nt < 2; ++nt)
#pragma unroll
    for (int c4 = 0; c4 < 4; ++c4)
      Bf[nt][c4] = *(const bf16x8*)&Pt[(w * 32 + nt * 16 + ln15) * PP + c4 * 32 + quad * 8];

  int p = 0;
  for (int t = 0; t < T_; ++t) {
    const unsigned short* zr = &ztb[p * 2176];
    unsigned short* zw = &ztb[(1 - p) * 2176];
    bf16x8 aF[4];
#pragma unroll
    for (int c4 = 0; c4 < 4; ++c4)
      aF[c4] = *(const bf16x8*)&zr[ln15 * 136 + c4 * 32 + quad * 8];
    f32x4 acc[2];
    acc[0] = (f32x4){0.f, 0.f, 0.f, 0.f};
    acc[1] = (f32x4){0.f, 0.f, 0.f, 0.f};
#pragma unroll
    for (int c4 = 0; c4 < 4; ++c4) {
      acc[0] = __builtin_amdgcn_mfma_f32_16x16x32_bf16(aF[c4], Bf[0][c4], acc[0], 0, 0, 0);
      acc[1] = __builtin_amdgcn_mfma_f32_16x16x32_bf16(aF[c4], Bf[1][c4], acc[1], 0, 0, 0);
    }
#pragma unroll
    for (int nt = 0; nt < 2; ++nt)
#pragma unroll
      for (int r = 0; r < 4; ++r) {
        const int row = quad * 4 + r;
        const int e = w * 32 + nt * 16 + ln15;
        const unsigned short hv = f32_to_bf16_rn(acc[nt][r]);
        zw[row * 136 + e] = hv;
        if (row < 8) Y[(((size_t)row * M_ + m) << 11) + (t << 7) + e] = hv;
      }
    __syncthreads();
    p ^= 1;
  }
}

// ---------------------------------------------------------------------------
// K3: iGFT via MFMA, B transposed from Y in-LDS, dual-XOR swizzled.
// out[t][b][n][e] = sum_m Ubf[b][n][m] * Y[b][m][t*128+e]
// 1-D grid(1024), XCD-pinned: b = bid%8 -> each XCD's L2 holds Ubf[b]
// (0.56 MB) + Y[b] (2 MB); the x16/x8 panel re-reads become L2 hits
// instead of L3 traffic (was ~135 MB of L3-served re-reads).
// ---------------------------------------------------------------------------
__global__ __launch_bounds__(256) void k3_igft(const unsigned short* __restrict__ Ubf,
                                               const unsigned short* __restrict__ Y,
                                               float* __restrict__ out) {
  __shared__ __align__(16) char smem[18432 + 16384];       // 34816 B
  unsigned short* As = (unsigned short*)smem;              // [128][72]
  unsigned short* Bs = (unsigned short*)(smem + 18432);    // [128][64] swizzled
  const int f0 = blockIdx.x;
  const int b = f0 & 7, rr = f0 >> 3;
  const int nb = rr & 7, tt = rr >> 3;
  const int n0 = nb * 128;
  const int tid = threadIdx.x, lane = tid & 63, w = tid >> 6;
  const int quad = lane >> 4, ln15 = lane & 15;
  const int hn = w >> 1, hv = w & 1;
  const unsigned short* Ua = Ubf + ((size_t)b * N_ + n0) * UB_STRIDE;
  const unsigned short* Ym = Y + ((size_t)b * M_) * 2048 + tt * 128;
  f32x4 acc[4][4];
#pragma unroll
  for (int i = 0; i < 4; ++i)
#pragma unroll
    for (int j = 0; j < 4; ++j) acc[i][j] = (f32x4){0.f, 0.f, 0.f, 0.f};
  for (int kc = 0; kc < 256; kc += 64) {
    __syncthreads();
#pragma unroll
    for (int p = 0; p < 4; ++p) {
      const int f = p * 256 + tid;
      const int r = f >> 3, u8 = (f & 7) * 8;
      *(uint4*)&As[r * 72 + u8] = *(const uint4*)&Ua[(size_t)r * UB_STRIDE + kc + u8];
    }
#pragma unroll
    for (int p = 0; p < 4; ++p) {
      const int f = p * 256 + tid;
      const int ml = f >> 4;         // local m 0..63
      const int te8 = (f & 15) * 8;  // te block
      const uint4 v = *(const uint4*)&Ym[(size_t)(kc + ml) * 2048 + te8];
      const unsigned short* sv = (const unsigned short*)&v;
      const int kb = ml >> 3, klo = ml & 7;
#pragma unroll
      for (int i = 0; i < 8; ++i) {
        const int te = te8 + i;
        const int blk = kb ^ ((te >> 3) & 7) ^ (te & 7);
        Bs[te * 64 + blk * 8 + klo] = sv[i];
      }
    }
    __syncthreads();
#pragma unroll
    for (int kc2 = 0; kc2 < 2; ++kc2) {
      bf16x8 aF[4], bF[4];
#pragma unroll
      for (int i = 0; i < 4; ++i)
        aF[i] = *(const bf16x8*)&As[(hn * 64 + 16 * i + ln15) * 72 + kc2 * 32 + quad * 8];
#pragma unroll
      for (int j = 0; j < 4; ++j) {
        const int row = hv * 64 + 16 * j + ln15;
        const int blk = (kc2 * 4 + quad) ^ ((row >> 3) & 7) ^ (row & 7);
        bF[j] = *(const bf16x8*)&Bs[row * 64 + blk * 8];
      }
#pragma unroll
      for (int i = 0; i < 4; ++i)
#pragma unroll
        for (int j = 0; j < 4; ++j)
          acc[i][j] = __builtin_amdgcn_mfma_f32_16x16x32_bf16(aF[i], bF[j], acc[i][j], 0, 0, 0);
    }
  }
  // direct C scatter: per store instr, 4 x 64B segments; r-unroll fills rows
  float* ob = out + ((size_t)tt * B_ + b) * N_ * E_ + (size_t)n0 * E_;
#pragma unroll
  for (int i = 0; i < 4; ++i)
#pragma unroll
    for (int j = 0; j < 4; ++j)
#pragma unroll
      for (int r = 0; r < 4; ++r) {
        const int n = hn * 64 + 16 * i + quad * 4 + r;
        const int e = hv * 64 + 16 * j + ln15;
        ob[(size_t)n * E_ + e] = acc[i][j][r];
      }
}

extern "C" void kernel_launch(void* const* d_in, const int* in_sizes, int n_in,
                              void* d_out, int out_size, void* d_ws, size_t ws_size,
                              hipStream_t stream) {
  const float* x = (const float*)d_in[0];
  // d_in[1] = times: fixed grid (i+1)/16 -> h = 1/16 constant
  const float* U = (const float*)d_in[2];
  const float* W = (const float*)d_in[3];
  float* out = (float*)d_out;

  // Disjoint layout in the 256 MiB workspace (no aliasing).
  char* ws = (char*)d_ws;
  float* xftp = (float*)ws;                                        //  0..16 MiB [8][M][B][E] f32 (8 MiB used)
  unsigned short* PgT = (unsigned short*)(ws + (16u << 20));       // 16..24 MiB [M][128][128] bf16 (P^T)
  unsigned short* Y = (unsigned short*)(ws + (24u << 20));         // 24..32 MiB [B][M][2048] bf16
  unsigned short* Ut = (unsigned short*)(ws + (32u << 20));        // 32..40 MiB [B][256][1088] bf16
  unsigned short* xt = (unsigned short*)(ws + (40u << 20));        // 40..44 MiB [B][128][1088] bf16
  unsigned short* Ubf = (unsigned short*)(ws + (44u << 20));       // 44..52 MiB [B][1024][272] bf16

  kprep<<<dim3(1024), 256, 0, stream>>>(U, x, W, Ubf, Ut, xt, PgT);
  k1_gft<<<dim3(256), 256, 0, stream>>>(Ut, xt, xftp);
  k2_ode<<<dim3(M_), 256, 0, stream>>>(xftp, PgT, Y);
  k3_igft<<<dim3(1024), 256, 0, stream>>>(Ubf, Y, out);
}